// Round 4
// baseline (218.529 us; speedup 1.0000x reference)
//
#include <hip/hip_runtime.h>
#include <math.h>

static constexpr int H = 512;
static constexpr int B = 64;
static constexpr int CSP = 8;   // context s-partitions
static constexpr int LSP = 16;  // log-softmax partitions

typedef __bf16 bf16x8 __attribute__((ext_vector_type(8)));
typedef __bf16 bf16x4 __attribute__((ext_vector_type(4)));
typedef float f32x4 __attribute__((ext_vector_type(4)));

__device__ __forceinline__ float sigmoidf_(float x) { return 1.f / (1.f + expf(-x)); }

// =====================================================================
// bf16-MFMA GEMM (LDS-staged): C[64][N] = A[64][K] @ W[N][K]^T + bias
// 64x64x64 tile, used for the small gi/gh GEMMs (K=512, N=1536).
// =====================================================================
__global__ __launch_bounds__(256) void gemm_mfma_nt(
    const float* __restrict__ A, const float* __restrict__ W,
    const float* __restrict__ bias, float* __restrict__ C,
    int K, int N, int ldc)
{
    __shared__ __bf16 As[2][64 * 64];
    __shared__ __bf16 Ws[2][64 * 64];

    const int tid  = threadIdx.x;
    const int lane = tid & 63;
    const int wv   = tid >> 6;
    const int n0   = blockIdx.x * 64;
    const int lrow = tid >> 2;
    const int lq   = tid & 3;

    int wrow = n0 + lrow;
    if (wrow > N - 1) wrow = N - 1;
    const float* Aptr = A + (size_t)lrow * K + lq * 16;
    const float* Wptr = W + (size_t)wrow * K + lq * 16;

    f32x4 acc[4] = {};
    float4 ra[4], rw[4];
    #pragma unroll
    for (int i = 0; i < 4; ++i) {
        ra[i] = *(const float4*)(Aptr + 4 * i);
        rw[i] = *(const float4*)(Wptr + 4 * i);
    }

    const int ln = lane & 15;
    const int lk = (lane >> 4) << 3;
    const int NT = K >> 6;

    for (int t = 0; t < NT; ++t) {
        __bf16* a_s = As[t & 1];
        __bf16* w_s = Ws[t & 1];
        #pragma unroll
        for (int i = 0; i < 4; ++i) {
            const int off = ((lrow << 6) + lq * 16 + 4 * i) ^ ((lrow & 7) << 3);
            *(bf16x4*)&a_s[off] = bf16x4{ (__bf16)ra[i].x, (__bf16)ra[i].y, (__bf16)ra[i].z, (__bf16)ra[i].w };
            *(bf16x4*)&w_s[off] = bf16x4{ (__bf16)rw[i].x, (__bf16)rw[i].y, (__bf16)rw[i].z, (__bf16)rw[i].w };
        }
        __syncthreads();
        if (t + 1 < NT) {
            const float* Ap = Aptr + (t + 1) * 64;
            const float* Wp = Wptr + (t + 1) * 64;
            #pragma unroll
            for (int i = 0; i < 4; ++i) {
                ra[i] = *(const float4*)(Ap + 4 * i);
                rw[i] = *(const float4*)(Wp + 4 * i);
            }
        }
        bf16x8 bfrag[2];
        #pragma unroll
        for (int ks = 0; ks < 2; ++ks) {
            const int row = wv * 16 + ln;
            const int off = ((row << 6) + ks * 32 + lk) ^ ((row & 7) << 3);
            bfrag[ks] = *(bf16x8*)&w_s[off];
        }
        #pragma unroll
        for (int m = 0; m < 4; ++m) {
            const int row = m * 16 + ln;
            #pragma unroll
            for (int ks = 0; ks < 2; ++ks) {
                const int off = ((row << 6) + ks * 32 + lk) ^ ((row & 7) << 3);
                bf16x8 afrag = *(bf16x8*)&a_s[off];
                acc[m] = __builtin_amdgcn_mfma_f32_16x16x32_bf16(afrag, bfrag[ks], acc[m], 0, 0, 0);
            }
        }
    }

    const int col = n0 + wv * 16 + ln;
    if (col < N) {
        const float bv = bias ? bias[col] : 0.f;
        #pragma unroll
        for (int m = 0; m < 4; ++m) {
            const int rbase = m * 16 + (lane >> 4) * 4;
            #pragma unroll
            for (int j = 0; j < 4; ++j)
                C[(size_t)(rbase + j) * ldc + col] = acc[m][j] + bv;
        }
    }
}

// =====================================================================
// Register-direct streaming bf16-MFMA GEMM for the huge output proj:
// C[64][N] = Ab[64][K](bf16) @ W[N][K](fp32->bf16 in-reg)^T + bias.
// NO LDS, NO barriers: W fragments loaded straight into the MFMA
// B-operand layout (lane l -> row n0+(l&15), k = ks*32+(l>>4)*8+j).
// A is tiny (128 KB bf16), L2-resident, loaded as 16B frags.
// Block = 4 waves, each wave owns 16 cols; grid = ceil(N/64).
// =====================================================================
__global__ __launch_bounds__(256, 4) void gemm_stream_nt(
    const __bf16* __restrict__ Ab,   // [64][K] bf16
    const float* __restrict__ W,     // [N][K] fp32
    const float* __restrict__ bias,
    float* __restrict__ C, int K, int N, int ldc)
{
    const int lane = threadIdx.x & 63;
    const int wv   = threadIdx.x >> 6;
    const int n0   = blockIdx.x * 64 + wv * 16;
    const int ln   = lane & 15;
    const int lk8  = (lane >> 4) << 3;   // 0,8,16,24

    int wr = n0 + ln;
    if (wr > N - 1) wr = N - 1;
    const float*  wp = W  + (size_t)wr * K + lk8;
    const __bf16* ap = Ab + (size_t)ln * K + lk8;

    f32x4 acc[4] = {};
    const int NKS = K >> 5;

    #pragma unroll 2
    for (int ks = 0; ks < NKS; ++ks) {
        const float4 w0 = *(const float4*)(wp);
        const float4 w1 = *(const float4*)(wp + 4);
        wp += 32;
        const bf16x8 bw = { (__bf16)w0.x, (__bf16)w0.y, (__bf16)w0.z, (__bf16)w0.w,
                            (__bf16)w1.x, (__bf16)w1.y, (__bf16)w1.z, (__bf16)w1.w };
        #pragma unroll
        for (int m = 0; m < 4; ++m) {
            const bf16x8 af = *(const bf16x8*)(ap + (size_t)m * 16 * K);
            acc[m] = __builtin_amdgcn_mfma_f32_16x16x32_bf16(af, bw, acc[m], 0, 0, 0);
        }
        ap += 32;
    }

    const int col = n0 + ln;
    if (col < N) {
        const float bv = bias[col];
        #pragma unroll
        for (int m = 0; m < 4; ++m) {
            const int rbase = m * 16 + (lane >> 4) * 4;
            #pragma unroll
            for (int j = 0; j < 4; ++j)
                C[(size_t)(rbase + j) * ldc + col] = acc[m][j] + bv;
        }
    }
}

// =====================================================================
// GRU gates (r,z,n): h' = (1-z)*n + z*h ; also writes bf16 combined[:, :H]
// =====================================================================
__global__ __launch_bounds__(512) void gru_gates(
    const float* __restrict__ gi, const float* __restrict__ gh,
    const float* __restrict__ h0, float* __restrict__ hnew,
    __bf16* __restrict__ cbf)
{
    const int b = blockIdx.x;
    const int h = threadIdx.x;
    const size_t o = (size_t)b * 3 * H;
    const float r = sigmoidf_(gi[o + h] + gh[o + h]);
    const float z = sigmoidf_(gi[o + H + h] + gh[o + H + h]);
    const float n = tanhf(gi[o + 2 * H + h] + r * gh[o + 2 * H + h]);
    const float hn = (1.f - z) * n + z * h0[(size_t)b * H + h];
    hnew[(size_t)b * H + h] = hn;
    cbf[(size_t)b * 2 * H + h] = (__bf16)hn;
}

// =====================================================================
// fp32 tiled GEMM, W in [K][N] layout (bilinear: tmp = hnew @ bilin_w)
// =====================================================================
__global__ __launch_bounds__(256) void gemm_a64_kn(
    const float* __restrict__ A, const float* __restrict__ W,
    float* __restrict__ C, int K, int N, int ldc)
{
    __shared__ float As[64][68];
    __shared__ float Bs[64][68];
    const int tid = threadIdx.x;
    const int n0 = blockIdx.x * 64;
    const int tv = tid & 15;
    const int tb = tid >> 4;
    const int lrow = tid >> 2;
    const int lk0  = (tid & 3) * 16;

    float acc[4][4] = {{0.f, 0.f, 0.f, 0.f}};

    for (int kc = 0; kc < K; kc += 64) {
        #pragma unroll
        for (int i = 0; i < 4; ++i) {
            const float4 a = *(const float4*)(A + (size_t)lrow * K + kc + lk0 + 4 * i);
            As[lk0 + 4 * i + 0][lrow] = a.x;
            As[lk0 + 4 * i + 1][lrow] = a.y;
            As[lk0 + 4 * i + 2][lrow] = a.z;
            As[lk0 + 4 * i + 3][lrow] = a.w;
        }
        {
            const int v  = tid & 63;
            const int kg = tid >> 6;
            #pragma unroll
            for (int i = 0; i < 16; ++i) {
                const int kk = kg * 16 + i;
                Bs[kk][v] = (n0 + v < N) ? W[(size_t)(kc + kk) * N + n0 + v] : 0.f;
            }
        }
        __syncthreads();
        #pragma unroll 16
        for (int kk = 0; kk < 64; ++kk) {
            const float4 a = *(const float4*)&As[kk][tb * 4];
            const float4 b = *(const float4*)&Bs[kk][tv * 4];
            acc[0][0] += a.x * b.x; acc[0][1] += a.x * b.y; acc[0][2] += a.x * b.z; acc[0][3] += a.x * b.w;
            acc[1][0] += a.y * b.x; acc[1][1] += a.y * b.y; acc[1][2] += a.y * b.z; acc[1][3] += a.y * b.w;
            acc[2][0] += a.z * b.x; acc[2][1] += a.z * b.y; acc[2][2] += a.z * b.z; acc[2][3] += a.z * b.w;
            acc[3][0] += a.w * b.x; acc[3][1] += a.w * b.y; acc[3][2] += a.w * b.z; acc[3][3] += a.w * b.w;
        }
        __syncthreads();
    }
    #pragma unroll
    for (int i = 0; i < 4; ++i) {
        const int bb = tb * 4 + i;
        #pragma unroll
        for (int j = 0; j < 4; ++j) {
            const int n = n0 + tv * 4 + j;
            if (n < N) C[(size_t)bb * ldc + n] = acc[i][j];
        }
    }
}

// =====================================================================
// energy[s][b] = dot(tmp[b,:], enc[s,b,:]) + bilin_b   (one wave per (s,b))
// =====================================================================
__global__ __launch_bounds__(256) void energy_k(
    const float* __restrict__ tmp, const float* __restrict__ enc,
    const float* __restrict__ bilin_b, float* __restrict__ energy, int S)
{
    const int gw = (int)((blockIdx.x * 256 + threadIdx.x) >> 6);
    const int lane = threadIdx.x & 63;
    if (gw >= S * B) return;
    const int s = gw >> 6;
    const int b = gw & 63;
    const float* e = enc + ((size_t)s * B + b) * H;
    const float* t = tmp + (size_t)b * H;
    const int k0 = lane * 8;
    const float4 e0 = *(const float4*)(e + k0);
    const float4 e1 = *(const float4*)(e + k0 + 4);
    const float4 t0 = *(const float4*)(t + k0);
    const float4 t1 = *(const float4*)(t + k0 + 4);
    float p = e0.x * t0.x + e0.y * t0.y + e0.z * t0.z + e0.w * t0.w
            + e1.x * t1.x + e1.y * t1.y + e1.z * t1.z + e1.w * t1.w;
    #pragma unroll
    for (int off = 32; off; off >>= 1) p += __shfl_down(p, off);
    if (lane == 0) energy[(size_t)s * B + b] = p + bilin_b[0];
}

// =====================================================================
// softmax over s for each column b
// =====================================================================
__global__ __launch_bounds__(128) void softmax_s(
    const float* __restrict__ energy, float* __restrict__ attn, int S)
{
    const int b = blockIdx.x;
    const int t = threadIdx.x;
    __shared__ float w0[2], w1[2];
    float m = -1e30f;
    for (int s = t; s < S; s += 128) m = fmaxf(m, energy[(size_t)s * B + b]);
    #pragma unroll
    for (int off = 32; off; off >>= 1) m = fmaxf(m, __shfl_xor(m, off));
    if ((t & 63) == 0) w0[t >> 6] = m;
    __syncthreads();
    m = fmaxf(w0[0], w0[1]);
    float sum = 0.f;
    for (int s = t; s < S; s += 128) sum += expf(energy[(size_t)s * B + b] - m);
    #pragma unroll
    for (int off = 32; off; off >>= 1) sum += __shfl_xor(sum, off);
    if ((t & 63) == 0) w1[t >> 6] = sum;
    __syncthreads();
    const float inv = 1.f / (w1[0] + w1[1]);
    for (int s = t; s < S; s += 128)
        attn[(size_t)s * B + b] = expf(energy[(size_t)s * B + b] - m) * inv;
}

// =====================================================================
// context partials over s-chunks
// =====================================================================
__global__ __launch_bounds__(512) void context_part(
    const float* __restrict__ attn, const float* __restrict__ enc,
    float* __restrict__ part, int S, int chunk)
{
    const int b = blockIdx.x;
    const int p = blockIdx.y;
    const int h = threadIdx.x;
    const int s0 = p * chunk;
    int s1 = s0 + chunk; if (s1 > S) s1 = S;
    __shared__ float a_s[128];
    if (h < s1 - s0) a_s[h] = attn[(size_t)(s0 + h) * B + b];
    __syncthreads();
    float c = 0.f;
    const float* e = enc + ((size_t)s0 * B + b) * H + h;
    for (int s = s0; s < s1; ++s, e += (size_t)B * H)
        c += a_s[s - s0] * (*e);
    part[((size_t)p * B + b) * H + h] = c;
}

__global__ __launch_bounds__(512) void context_reduce(
    const float* __restrict__ part, __bf16* __restrict__ cbf)
{
    const int b = blockIdx.x;
    const int h = threadIdx.x;
    float c = 0.f;
    #pragma unroll
    for (int p = 0; p < CSP; ++p) c += part[((size_t)p * B + b) * H + h];
    cbf[(size_t)b * 2 * H + H + h] = (__bf16)c;
}

// =====================================================================
// log_softmax, 3-stage
// =====================================================================
__global__ __launch_bounds__(256) void lsm_part(
    const float* __restrict__ logits, float* __restrict__ pm,
    float* __restrict__ ps, int V)
{
    const int b = blockIdx.x;
    const int p = blockIdx.y;
    const int t = threadIdx.x;
    const int V4 = V >> 2;
    const int chunk = (V4 + LSP - 1) / LSP;
    const int i0 = p * chunk;
    int i1 = i0 + chunk; if (i1 > V4) i1 = V4;
    const float4* row = (const float4*)(logits + (size_t)b * V);
    __shared__ float sm[4], ss[4];

    float m = -1e30f;
    for (int i = i0 + t; i < i1; i += 256) {
        const float4 v = row[i];
        m = fmaxf(fmaxf(fmaxf(m, v.x), v.y), fmaxf(v.z, v.w));
    }
    #pragma unroll
    for (int off = 32; off; off >>= 1) m = fmaxf(m, __shfl_xor(m, off));
    if ((t & 63) == 0) sm[t >> 6] = m;
    __syncthreads();
    m = fmaxf(fmaxf(sm[0], sm[1]), fmaxf(sm[2], sm[3]));

    float s = 0.f;
    for (int i = i0 + t; i < i1; i += 256) {
        const float4 v = row[i];
        s += expf(v.x - m) + expf(v.y - m) + expf(v.z - m) + expf(v.w - m);
    }
    #pragma unroll
    for (int off = 32; off; off >>= 1) s += __shfl_xor(s, off);
    if ((t & 63) == 0) ss[t >> 6] = s;
    __syncthreads();
    if (t == 0) {
        pm[b * LSP + p] = m;
        ps[b * LSP + p] = ss[0] + ss[1] + ss[2] + ss[3];
    }
}

__global__ __launch_bounds__(64) void lsm_combine(
    const float* __restrict__ pm, const float* __restrict__ ps,
    float* __restrict__ c)
{
    const int b = blockIdx.x;
    const int l = threadIdx.x;
    float m = (l < LSP) ? pm[b * LSP + l] : -1e30f;
    float mm = m;
    #pragma unroll
    for (int off = 32; off; off >>= 1) mm = fmaxf(mm, __shfl_xor(mm, off));
    float s = (l < LSP) ? ps[b * LSP + l] * expf(m - mm) : 0.f;
    #pragma unroll
    for (int off = 32; off; off >>= 1) s += __shfl_xor(s, off);
    if (l == 0) c[b] = mm + logf(s);
}

__global__ __launch_bounds__(256) void lsm_apply(
    float* __restrict__ logits, const float* __restrict__ c, int V)
{
    const int b = blockIdx.y;
    const int i = blockIdx.x * 256 + threadIdx.x;
    const int V4 = V >> 2;
    if (i >= V4) return;
    float4* row = (float4*)(logits + (size_t)b * V);
    float4 v = row[i];
    const float cb = c[b];
    v.x -= cb; v.y -= cb; v.z -= cb; v.w -= cb;
    row[i] = v;
}

// =====================================================================
extern "C" void kernel_launch(void* const* d_in, const int* in_sizes, int n_in,
                              void* d_out, int out_size, void* d_ws, size_t ws_size,
                              hipStream_t stream)
{
    const float* embedded = (const float*)d_in[0];
    const float* hidden   = (const float*)d_in[1];
    const float* enc      = (const float*)d_in[2];
    const float* w_ih     = (const float*)d_in[3];
    const float* w_hh     = (const float*)d_in[4];
    const float* b_ih     = (const float*)d_in[5];
    const float* b_hh     = (const float*)d_in[6];
    const float* bilin_w  = (const float*)d_in[7];
    const float* bilin_b  = (const float*)d_in[8];
    const float* out_w    = (const float*)d_in[9];
    const float* out_b    = (const float*)d_in[10];
    float* out = (float*)d_out;

    const int E = in_sizes[0] / B;            // 512
    const int S = in_sizes[2] / (B * H);      // 400
    const int V = in_sizes[9] / (2 * H);      // 50000

    float* logp = out;
    float* hnew = out + (size_t)B * V;
    float* attn = hnew + (size_t)B * H;

    float* ws     = (float*)d_ws;
    float* gi     = ws;                        // B*3H
    float* gh     = gi + (size_t)B * 3 * H;    // B*3H
    float* tmp    = gh + (size_t)B * 3 * H;    // B*H
    float* energy = tmp + (size_t)B * H;       // S*B
    float* part   = energy + (size_t)S * B;    // CSP*B*H
    float* pm     = part + (size_t)CSP * B * H;// B*LSP
    float* ps     = pm + (size_t)B * LSP;      // B*LSP
    float* cb     = ps + (size_t)B * LSP;      // B
    __bf16* cbf   = (__bf16*)(cb + 64);        // B*2H bf16 (combined)

    // 1) gi / gh (bf16 MFMA, LDS-staged)
    gemm_mfma_nt<<<(3 * H) / 64, 256, 0, stream>>>(embedded, w_ih, b_ih, gi, E, 3 * H, 3 * H);
    gemm_mfma_nt<<<(3 * H) / 64, 256, 0, stream>>>(hidden, w_hh, b_hh, gh, H, 3 * H, 3 * H);

    // 2) GRU gates -> hnew (d_out fp32) + cbf[:, :H] (bf16)
    gru_gates<<<B, H, 0, stream>>>(gi, gh, hidden, hnew, cbf);

    // 3) tmp = hnew @ bilin_w[0]
    gemm_a64_kn<<<H / 64, 256, 0, stream>>>(hnew, bilin_w, tmp, H, H, H);

    // 4) energy
    energy_k<<<(S * B + 3) / 4, 256, 0, stream>>>(tmp, enc, bilin_b, energy, S);

    // 5) attn
    softmax_s<<<B, 128, 0, stream>>>(energy, attn, S);

    // 6) context -> cbf[:, H:] (bf16)
    const int chunk = (S + CSP - 1) / CSP;
    context_part<<<dim3(B, CSP), 512, 0, stream>>>(attn, enc, part, S, chunk);
    context_reduce<<<B, 512, 0, stream>>>(part, cbf);

    // 7) logits = cbf @ out_w^T + out_b  (register-direct streaming MFMA)
    gemm_stream_nt<<<(V + 63) / 64, 256, 0, stream>>>(cbf, out_w, out_b, logp, 2 * H, V, V);

    // 8) log_softmax
    lsm_part<<<dim3(B, LSP), 256, 0, stream>>>(logp, pm, ps, V);
    lsm_combine<<<B, 64, 0, stream>>>(pm, ps, cb);
    lsm_apply<<<dim3((V / 4 + 255) / 256, B), 256, 0, stream>>>(logp, cb, V);
}

// Round 5
// 181.281 us; speedup vs baseline: 1.2055x; 1.2055x over previous
//
#include <hip/hip_runtime.h>
#include <math.h>

static constexpr int H = 512;
static constexpr int B = 64;
static constexpr int CSP = 8;   // context s-partitions
static constexpr int LSP = 16;  // log-softmax partitions

typedef __bf16 bf16x8 __attribute__((ext_vector_type(8)));
typedef __bf16 bf16x4 __attribute__((ext_vector_type(4)));
typedef float f32x4 __attribute__((ext_vector_type(4)));

__device__ __forceinline__ float sigmoidf_(float x) { return 1.f / (1.f + expf(-x)); }

// =====================================================================
// bf16-MFMA GEMM (LDS-staged): C[64][N] = A[64][K] @ W[N][K]^T + bias
// 64x64x64 tile, used for the small gi/gh GEMMs (K=512, N=1536).
// =====================================================================
__global__ __launch_bounds__(256) void gemm_mfma_nt(
    const float* __restrict__ A, const float* __restrict__ W,
    const float* __restrict__ bias, float* __restrict__ C,
    int K, int N, int ldc)
{
    __shared__ __bf16 As[2][64 * 64];
    __shared__ __bf16 Ws[2][64 * 64];

    const int tid  = threadIdx.x;
    const int lane = tid & 63;
    const int wv   = tid >> 6;
    const int n0   = blockIdx.x * 64;
    const int lrow = tid >> 2;
    const int lq   = tid & 3;

    int wrow = n0 + lrow;
    if (wrow > N - 1) wrow = N - 1;
    const float* Aptr = A + (size_t)lrow * K + lq * 16;
    const float* Wptr = W + (size_t)wrow * K + lq * 16;

    f32x4 acc[4] = {};
    float4 ra[4], rw[4];
    #pragma unroll
    for (int i = 0; i < 4; ++i) {
        ra[i] = *(const float4*)(Aptr + 4 * i);
        rw[i] = *(const float4*)(Wptr + 4 * i);
    }

    const int ln = lane & 15;
    const int lk = (lane >> 4) << 3;
    const int NT = K >> 6;

    for (int t = 0; t < NT; ++t) {
        __bf16* a_s = As[t & 1];
        __bf16* w_s = Ws[t & 1];
        #pragma unroll
        for (int i = 0; i < 4; ++i) {
            const int off = ((lrow << 6) + lq * 16 + 4 * i) ^ ((lrow & 7) << 3);
            *(bf16x4*)&a_s[off] = bf16x4{ (__bf16)ra[i].x, (__bf16)ra[i].y, (__bf16)ra[i].z, (__bf16)ra[i].w };
            *(bf16x4*)&w_s[off] = bf16x4{ (__bf16)rw[i].x, (__bf16)rw[i].y, (__bf16)rw[i].z, (__bf16)rw[i].w };
        }
        __syncthreads();
        if (t + 1 < NT) {
            const float* Ap = Aptr + (t + 1) * 64;
            const float* Wp = Wptr + (t + 1) * 64;
            #pragma unroll
            for (int i = 0; i < 4; ++i) {
                ra[i] = *(const float4*)(Ap + 4 * i);
                rw[i] = *(const float4*)(Wp + 4 * i);
            }
        }
        bf16x8 bfrag[2];
        #pragma unroll
        for (int ks = 0; ks < 2; ++ks) {
            const int row = wv * 16 + ln;
            const int off = ((row << 6) + ks * 32 + lk) ^ ((row & 7) << 3);
            bfrag[ks] = *(bf16x8*)&w_s[off];
        }
        #pragma unroll
        for (int m = 0; m < 4; ++m) {
            const int row = m * 16 + ln;
            #pragma unroll
            for (int ks = 0; ks < 2; ++ks) {
                const int off = ((row << 6) + ks * 32 + lk) ^ ((row & 7) << 3);
                bf16x8 afrag = *(bf16x8*)&a_s[off];
                acc[m] = __builtin_amdgcn_mfma_f32_16x16x32_bf16(afrag, bfrag[ks], acc[m], 0, 0, 0);
            }
        }
    }

    const int col = n0 + wv * 16 + ln;
    if (col < N) {
        const float bv = bias ? bias[col] : 0.f;
        #pragma unroll
        for (int m = 0; m < 4; ++m) {
            const int rbase = m * 16 + (lane >> 4) * 4;
            #pragma unroll
            for (int j = 0; j < 4; ++j)
                C[(size_t)(rbase + j) * ldc + col] = acc[m][j] + bv;
        }
    }
}

// =====================================================================
// Big output projection: C[64][N] = Ab[64][K](bf16) @ W[N][K](fp32)^T + b
// W streams register-direct (pure vmcnt pipeline, offsets are immediates);
// A-panel staged in LDS in four 32KB quarters (swizzled), read via
// ds_read_b128 (lgkmcnt queue - decoupled from the W stream).
// Block = 256 thr / 4 waves; wave owns 16 cols; grid = ceil(N/64).
// =====================================================================
__global__ __launch_bounds__(256) void gemm_stream_lds(
    const __bf16* __restrict__ Ab,   // [64][K] bf16
    const float* __restrict__ W,     // [N][K] fp32
    const float* __restrict__ bias,
    float* __restrict__ C, int K, int N, int ldc)
{
    __shared__ __bf16 As[64 * 256];  // one 32 KB quarter (K-slice of 256)

    const int tid  = threadIdx.x;
    const int lane = tid & 63;
    const int wv   = tid >> 6;
    const int n0   = blockIdx.x * 64 + wv * 16;
    const int ln   = lane & 15;
    const int lk8  = (lane >> 4) << 3;   // 0,8,16,24

    int wr = n0 + ln;
    if (wr > N - 1) wr = N - 1;
    const float* wp = W + (size_t)wr * K + lk8;

    f32x4 acc[4] = {};
    const int NQ = K >> 8;               // quarters of 256 k-elems

    for (int q = 0; q < NQ; ++q) {
        __syncthreads();
        // ---- stage A quarter q: 64 rows x 256 k (bf16), swizzled ----
        #pragma unroll
        for (int i = 0; i < 8; ++i) {
            const int c   = tid + i * 256;       // chunk id, 2048 total
            const int row = c >> 5;              // 32 chunks per row
            const int eb  = (c & 31) << 3;       // elem base in row
            const bf16x8 v = *(const bf16x8*)(Ab + (size_t)row * K + q * 256 + eb);
            const int off = (row << 8) + (eb ^ ((row & 7) << 3));
            *(bf16x8*)&As[off] = v;
        }
        __syncthreads();
        // ---- stream W over this k-quarter: 8 steps of 32 ----
        #pragma unroll
        for (int ks = 0; ks < 8; ++ks) {
            const float4 w0 = *(const float4*)(wp + q * 256 + ks * 32);
            const float4 w1 = *(const float4*)(wp + q * 256 + ks * 32 + 4);
            const bf16x8 bw = { (__bf16)w0.x, (__bf16)w0.y, (__bf16)w0.z, (__bf16)w0.w,
                                (__bf16)w1.x, (__bf16)w1.y, (__bf16)w1.z, (__bf16)w1.w };
            #pragma unroll
            for (int m = 0; m < 4; ++m) {
                const int row = m * 16 + ln;
                const int off = (row << 8) + ((ks * 32 + lk8) ^ ((row & 7) << 3));
                const bf16x8 af = *(const bf16x8*)&As[off];
                acc[m] = __builtin_amdgcn_mfma_f32_16x16x32_bf16(af, bw, acc[m], 0, 0, 0);
            }
        }
    }

    const int col = n0 + ln;
    if (col < N) {
        const float bv = bias[col];
        #pragma unroll
        for (int m = 0; m < 4; ++m) {
            const int rbase = m * 16 + (lane >> 4) * 4;
            #pragma unroll
            for (int j = 0; j < 4; ++j)
                C[(size_t)(rbase + j) * ldc + col] = acc[m][j] + bv;
        }
    }
}

// =====================================================================
// GRU gates (r,z,n): h' = (1-z)*n + z*h ; also writes bf16 combined[:, :H]
// =====================================================================
__global__ __launch_bounds__(512) void gru_gates(
    const float* __restrict__ gi, const float* __restrict__ gh,
    const float* __restrict__ h0, float* __restrict__ hnew,
    __bf16* __restrict__ cbf)
{
    const int b = blockIdx.x;
    const int h = threadIdx.x;
    const size_t o = (size_t)b * 3 * H;
    const float r = sigmoidf_(gi[o + h] + gh[o + h]);
    const float z = sigmoidf_(gi[o + H + h] + gh[o + H + h]);
    const float n = tanhf(gi[o + 2 * H + h] + r * gh[o + 2 * H + h]);
    const float hn = (1.f - z) * n + z * h0[(size_t)b * H + h];
    hnew[(size_t)b * H + h] = hn;
    cbf[(size_t)b * 2 * H + h] = (__bf16)hn;
}

// =====================================================================
// fp32 tiled GEMM, W in [K][N] layout (bilinear: tmp = hnew @ bilin_w)
// =====================================================================
__global__ __launch_bounds__(256) void gemm_a64_kn(
    const float* __restrict__ A, const float* __restrict__ W,
    float* __restrict__ C, int K, int N, int ldc)
{
    __shared__ float As[64][68];
    __shared__ float Bs[64][68];
    const int tid = threadIdx.x;
    const int n0 = blockIdx.x * 64;
    const int tv = tid & 15;
    const int tb = tid >> 4;
    const int lrow = tid >> 2;
    const int lk0  = (tid & 3) * 16;

    float acc[4][4] = {{0.f, 0.f, 0.f, 0.f}};

    for (int kc = 0; kc < K; kc += 64) {
        #pragma unroll
        for (int i = 0; i < 4; ++i) {
            const float4 a = *(const float4*)(A + (size_t)lrow * K + kc + lk0 + 4 * i);
            As[lk0 + 4 * i + 0][lrow] = a.x;
            As[lk0 + 4 * i + 1][lrow] = a.y;
            As[lk0 + 4 * i + 2][lrow] = a.z;
            As[lk0 + 4 * i + 3][lrow] = a.w;
        }
        {
            const int v  = tid & 63;
            const int kg = tid >> 6;
            #pragma unroll
            for (int i = 0; i < 16; ++i) {
                const int kk = kg * 16 + i;
                Bs[kk][v] = (n0 + v < N) ? W[(size_t)(kc + kk) * N + n0 + v] : 0.f;
            }
        }
        __syncthreads();
        #pragma unroll 16
        for (int kk = 0; kk < 64; ++kk) {
            const float4 a = *(const float4*)&As[kk][tb * 4];
            const float4 b = *(const float4*)&Bs[kk][tv * 4];
            acc[0][0] += a.x * b.x; acc[0][1] += a.x * b.y; acc[0][2] += a.x * b.z; acc[0][3] += a.x * b.w;
            acc[1][0] += a.y * b.x; acc[1][1] += a.y * b.y; acc[1][2] += a.y * b.z; acc[1][3] += a.y * b.w;
            acc[2][0] += a.z * b.x; acc[2][1] += a.z * b.y; acc[2][2] += a.z * b.z; acc[2][3] += a.z * b.w;
            acc[3][0] += a.w * b.x; acc[3][1] += a.w * b.y; acc[3][2] += a.w * b.z; acc[3][3] += a.w * b.w;
        }
        __syncthreads();
    }
    #pragma unroll
    for (int i = 0; i < 4; ++i) {
        const int bb = tb * 4 + i;
        #pragma unroll
        for (int j = 0; j < 4; ++j) {
            const int n = n0 + tv * 4 + j;
            if (n < N) C[(size_t)bb * ldc + n] = acc[i][j];
        }
    }
}

// =====================================================================
// energy[s][b] = dot(tmp[b,:], enc[s,b,:]) + bilin_b   (one wave per (s,b))
// =====================================================================
__global__ __launch_bounds__(256) void energy_k(
    const float* __restrict__ tmp, const float* __restrict__ enc,
    const float* __restrict__ bilin_b, float* __restrict__ energy, int S)
{
    const int gw = (int)((blockIdx.x * 256 + threadIdx.x) >> 6);
    const int lane = threadIdx.x & 63;
    if (gw >= S * B) return;
    const int s = gw >> 6;
    const int b = gw & 63;
    const float* e = enc + ((size_t)s * B + b) * H;
    const float* t = tmp + (size_t)b * H;
    const int k0 = lane * 8;
    const float4 e0 = *(const float4*)(e + k0);
    const float4 e1 = *(const float4*)(e + k0 + 4);
    const float4 t0 = *(const float4*)(t + k0);
    const float4 t1 = *(const float4*)(t + k0 + 4);
    float p = e0.x * t0.x + e0.y * t0.y + e0.z * t0.z + e0.w * t0.w
            + e1.x * t1.x + e1.y * t1.y + e1.z * t1.z + e1.w * t1.w;
    #pragma unroll
    for (int off = 32; off; off >>= 1) p += __shfl_down(p, off);
    if (lane == 0) energy[(size_t)s * B + b] = p + bilin_b[0];
}

// =====================================================================
// softmax over s for each column b
// =====================================================================
__global__ __launch_bounds__(128) void softmax_s(
    const float* __restrict__ energy, float* __restrict__ attn, int S)
{
    const int b = blockIdx.x;
    const int t = threadIdx.x;
    __shared__ float w0[2], w1[2];
    float m = -1e30f;
    for (int s = t; s < S; s += 128) m = fmaxf(m, energy[(size_t)s * B + b]);
    #pragma unroll
    for (int off = 32; off; off >>= 1) m = fmaxf(m, __shfl_xor(m, off));
    if ((t & 63) == 0) w0[t >> 6] = m;
    __syncthreads();
    m = fmaxf(w0[0], w0[1]);
    float sum = 0.f;
    for (int s = t; s < S; s += 128) sum += expf(energy[(size_t)s * B + b] - m);
    #pragma unroll
    for (int off = 32; off; off >>= 1) sum += __shfl_xor(sum, off);
    if ((t & 63) == 0) w1[t >> 6] = sum;
    __syncthreads();
    const float inv = 1.f / (w1[0] + w1[1]);
    for (int s = t; s < S; s += 128)
        attn[(size_t)s * B + b] = expf(energy[(size_t)s * B + b] - m) * inv;
}

// =====================================================================
// context partials over s-chunks
// =====================================================================
__global__ __launch_bounds__(512) void context_part(
    const float* __restrict__ attn, const float* __restrict__ enc,
    float* __restrict__ part, int S, int chunk)
{
    const int b = blockIdx.x;
    const int p = blockIdx.y;
    const int h = threadIdx.x;
    const int s0 = p * chunk;
    int s1 = s0 + chunk; if (s1 > S) s1 = S;
    __shared__ float a_s[128];
    if (h < s1 - s0) a_s[h] = attn[(size_t)(s0 + h) * B + b];
    __syncthreads();
    float c = 0.f;
    const float* e = enc + ((size_t)s0 * B + b) * H + h;
    for (int s = s0; s < s1; ++s, e += (size_t)B * H)
        c += a_s[s - s0] * (*e);
    part[((size_t)p * B + b) * H + h] = c;
}

__global__ __launch_bounds__(512) void context_reduce(
    const float* __restrict__ part, __bf16* __restrict__ cbf)
{
    const int b = blockIdx.x;
    const int h = threadIdx.x;
    float c = 0.f;
    #pragma unroll
    for (int p = 0; p < CSP; ++p) c += part[((size_t)p * B + b) * H + h];
    cbf[(size_t)b * 2 * H + H + h] = (__bf16)c;
}

// =====================================================================
// log_softmax, 3-stage
// =====================================================================
__global__ __launch_bounds__(256) void lsm_part(
    const float* __restrict__ logits, float* __restrict__ pm,
    float* __restrict__ ps, int V)
{
    const int b = blockIdx.x;
    const int p = blockIdx.y;
    const int t = threadIdx.x;
    const int V4 = V >> 2;
    const int chunk = (V4 + LSP - 1) / LSP;
    const int i0 = p * chunk;
    int i1 = i0 + chunk; if (i1 > V4) i1 = V4;
    const float4* row = (const float4*)(logits + (size_t)b * V);
    __shared__ float sm[4], ss[4];

    float m = -1e30f;
    for (int i = i0 + t; i < i1; i += 256) {
        const float4 v = row[i];
        m = fmaxf(fmaxf(fmaxf(m, v.x), v.y), fmaxf(v.z, v.w));
    }
    #pragma unroll
    for (int off = 32; off; off >>= 1) m = fmaxf(m, __shfl_xor(m, off));
    if ((t & 63) == 0) sm[t >> 6] = m;
    __syncthreads();
    m = fmaxf(fmaxf(sm[0], sm[1]), fmaxf(sm[2], sm[3]));

    float s = 0.f;
    for (int i = i0 + t; i < i1; i += 256) {
        const float4 v = row[i];
        s += expf(v.x - m) + expf(v.y - m) + expf(v.z - m) + expf(v.w - m);
    }
    #pragma unroll
    for (int off = 32; off; off >>= 1) s += __shfl_xor(s, off);
    if ((t & 63) == 0) ss[t >> 6] = s;
    __syncthreads();
    if (t == 0) {
        pm[b * LSP + p] = m;
        ps[b * LSP + p] = ss[0] + ss[1] + ss[2] + ss[3];
    }
}

__global__ __launch_bounds__(64) void lsm_combine(
    const float* __restrict__ pm, const float* __restrict__ ps,
    float* __restrict__ c)
{
    const int b = blockIdx.x;
    const int l = threadIdx.x;
    float m = (l < LSP) ? pm[b * LSP + l] : -1e30f;
    float mm = m;
    #pragma unroll
    for (int off = 32; off; off >>= 1) mm = fmaxf(mm, __shfl_xor(mm, off));
    float s = (l < LSP) ? ps[b * LSP + l] * expf(m - mm) : 0.f;
    #pragma unroll
    for (int off = 32; off; off >>= 1) s += __shfl_xor(s, off);
    if (l == 0) c[b] = mm + logf(s);
}

__global__ __launch_bounds__(256) void lsm_apply(
    float* __restrict__ logits, const float* __restrict__ c, int V)
{
    const int b = blockIdx.y;
    const int i = blockIdx.x * 256 + threadIdx.x;
    const int V4 = V >> 2;
    if (i >= V4) return;
    float4* row = (float4*)(logits + (size_t)b * V);
    float4 v = row[i];
    const float cb = c[b];
    v.x -= cb; v.y -= cb; v.z -= cb; v.w -= cb;
    row[i] = v;
}

// =====================================================================
extern "C" void kernel_launch(void* const* d_in, const int* in_sizes, int n_in,
                              void* d_out, int out_size, void* d_ws, size_t ws_size,
                              hipStream_t stream)
{
    const float* embedded = (const float*)d_in[0];
    const float* hidden   = (const float*)d_in[1];
    const float* enc      = (const float*)d_in[2];
    const float* w_ih     = (const float*)d_in[3];
    const float* w_hh     = (const float*)d_in[4];
    const float* b_ih     = (const float*)d_in[5];
    const float* b_hh     = (const float*)d_in[6];
    const float* bilin_w  = (const float*)d_in[7];
    const float* bilin_b  = (const float*)d_in[8];
    const float* out_w    = (const float*)d_in[9];
    const float* out_b    = (const float*)d_in[10];
    float* out = (float*)d_out;

    const int E = in_sizes[0] / B;            // 512
    const int S = in_sizes[2] / (B * H);      // 400
    const int V = in_sizes[9] / (2 * H);      // 50000

    float* logp = out;
    float* hnew = out + (size_t)B * V;
    float* attn = hnew + (size_t)B * H;

    float* ws     = (float*)d_ws;
    float* gi     = ws;                        // B*3H
    float* gh     = gi + (size_t)B * 3 * H;    // B*3H
    float* tmp    = gh + (size_t)B * 3 * H;    // B*H
    float* energy = tmp + (size_t)B * H;       // S*B
    float* part   = energy + (size_t)S * B;    // CSP*B*H
    float* pm     = part + (size_t)CSP * B * H;// B*LSP
    float* ps     = pm + (size_t)B * LSP;      // B*LSP
    float* cb     = ps + (size_t)B * LSP;      // B
    __bf16* cbf   = (__bf16*)(cb + 64);        // B*2H bf16 (combined), 16B-aligned

    // 1) gi / gh (bf16 MFMA, LDS-staged)
    gemm_mfma_nt<<<(3 * H) / 64, 256, 0, stream>>>(embedded, w_ih, b_ih, gi, E, 3 * H, 3 * H);
    gemm_mfma_nt<<<(3 * H) / 64, 256, 0, stream>>>(hidden, w_hh, b_hh, gh, H, 3 * H, 3 * H);

    // 2) GRU gates -> hnew (d_out fp32) + cbf[:, :H] (bf16)
    gru_gates<<<B, H, 0, stream>>>(gi, gh, hidden, hnew, cbf);

    // 3) tmp = hnew @ bilin_w[0]
    gemm_a64_kn<<<H / 64, 256, 0, stream>>>(hnew, bilin_w, tmp, H, H, H);

    // 4) energy
    energy_k<<<(S * B + 3) / 4, 256, 0, stream>>>(tmp, enc, bilin_b, energy, S);

    // 5) attn
    softmax_s<<<B, 128, 0, stream>>>(energy, attn, S);

    // 6) context -> cbf[:, H:] (bf16)
    const int chunk = (S + CSP - 1) / CSP;
    context_part<<<dim3(B, CSP), 512, 0, stream>>>(attn, enc, part, S, chunk);
    context_reduce<<<B, 512, 0, stream>>>(part, cbf);

    // 7) logits = cbf @ out_w^T + out_b  (W-stream + A-in-LDS MFMA)
    gemm_stream_lds<<<(V + 63) / 64, 256, 0, stream>>>(cbf, out_w, out_b, logp, 2 * H, V, V);

    // 8) log_softmax
    lsm_part<<<dim3(B, LSP), 256, 0, stream>>>(logp, pm, ps, V);
    lsm_combine<<<B, 64, 0, stream>>>(pm, ps, cb);
    lsm_apply<<<dim3((V / 4 + 255) / 256, B), 256, 0, stream>>>(logp, cb, V);
}

// Round 6
// 153.202 us; speedup vs baseline: 1.4264x; 1.1833x over previous
//
#include <hip/hip_runtime.h>
#include <math.h>

static constexpr int H = 512;
static constexpr int B = 64;
static constexpr int FP = 8;    // flash attention s-partitions

typedef __bf16 bf16x8 __attribute__((ext_vector_type(8)));
typedef __bf16 bf16x4 __attribute__((ext_vector_type(4)));
typedef float f32x4 __attribute__((ext_vector_type(4)));

__device__ __forceinline__ float sigmoidf_(float x) { return 1.f / (1.f + expf(-x)); }

// =====================================================================
// gi/gh GEMMs in one launch: blockIdx.y=0 -> gi = embedded @ w_ih^T
//                            blockIdx.y=1 -> gh = hidden   @ w_hh^T
// (biases applied later in gru_gates). 64x64x64 MFMA tile, K=512, N=1536.
// =====================================================================
__global__ __launch_bounds__(256) void gemm_gigh(
    const float* __restrict__ embedded, const float* __restrict__ hidden,
    const float* __restrict__ w_ih, const float* __restrict__ w_hh,
    float* __restrict__ gi, float* __restrict__ gh, int K, int N)
{
    const float* A = blockIdx.y ? hidden : embedded;
    const float* W = blockIdx.y ? w_hh : w_ih;
    float* C       = blockIdx.y ? gh : gi;

    __shared__ __bf16 As[2][64 * 64];
    __shared__ __bf16 Ws[2][64 * 64];

    const int tid  = threadIdx.x;
    const int lane = tid & 63;
    const int wv   = tid >> 6;
    const int n0   = blockIdx.x * 64;
    const int lrow = tid >> 2;
    const int lq   = tid & 3;

    const float* Aptr = A + (size_t)lrow * K + lq * 16;
    const float* Wptr = W + (size_t)(n0 + lrow) * K + lq * 16;

    f32x4 acc[4] = {};
    float4 ra[4], rw[4];
    #pragma unroll
    for (int i = 0; i < 4; ++i) {
        ra[i] = *(const float4*)(Aptr + 4 * i);
        rw[i] = *(const float4*)(Wptr + 4 * i);
    }

    const int ln = lane & 15;
    const int lk = (lane >> 4) << 3;
    const int NT = K >> 6;

    for (int t = 0; t < NT; ++t) {
        __bf16* a_s = As[t & 1];
        __bf16* w_s = Ws[t & 1];
        #pragma unroll
        for (int i = 0; i < 4; ++i) {
            const int off = ((lrow << 6) + lq * 16 + 4 * i) ^ ((lrow & 7) << 3);
            *(bf16x4*)&a_s[off] = bf16x4{ (__bf16)ra[i].x, (__bf16)ra[i].y, (__bf16)ra[i].z, (__bf16)ra[i].w };
            *(bf16x4*)&w_s[off] = bf16x4{ (__bf16)rw[i].x, (__bf16)rw[i].y, (__bf16)rw[i].z, (__bf16)rw[i].w };
        }
        __syncthreads();
        if (t + 1 < NT) {
            const float* Ap = Aptr + (t + 1) * 64;
            const float* Wp = Wptr + (t + 1) * 64;
            #pragma unroll
            for (int i = 0; i < 4; ++i) {
                ra[i] = *(const float4*)(Ap + 4 * i);
                rw[i] = *(const float4*)(Wp + 4 * i);
            }
        }
        bf16x8 bfrag[2];
        #pragma unroll
        for (int ks = 0; ks < 2; ++ks) {
            const int row = wv * 16 + ln;
            const int off = ((row << 6) + ks * 32 + lk) ^ ((row & 7) << 3);
            bfrag[ks] = *(bf16x8*)&w_s[off];
        }
        #pragma unroll
        for (int m = 0; m < 4; ++m) {
            const int row = m * 16 + ln;
            #pragma unroll
            for (int ks = 0; ks < 2; ++ks) {
                const int off = ((row << 6) + ks * 32 + lk) ^ ((row & 7) << 3);
                bf16x8 afrag = *(bf16x8*)&a_s[off];
                acc[m] = __builtin_amdgcn_mfma_f32_16x16x32_bf16(afrag, bfrag[ks], acc[m], 0, 0, 0);
            }
        }
    }

    const int col = n0 + wv * 16 + ln;
    #pragma unroll
    for (int m = 0; m < 4; ++m) {
        const int rbase = m * 16 + (lane >> 4) * 4;
        #pragma unroll
        for (int j = 0; j < 4; ++j)
            C[(size_t)(rbase + j) * N + col] = acc[m][j];
    }
}

// =====================================================================
// GRU gates (r,z,n) with bias application; writes hnew fp32 + bf16 cbf
// =====================================================================
__global__ __launch_bounds__(512) void gru_gates(
    const float* __restrict__ gi, const float* __restrict__ gh,
    const float* __restrict__ b_ih, const float* __restrict__ b_hh,
    const float* __restrict__ h0, float* __restrict__ hnew,
    __bf16* __restrict__ cbf)
{
    const int b = blockIdx.x;
    const int h = threadIdx.x;
    const size_t o = (size_t)b * 3 * H;
    const float r = sigmoidf_(gi[o + h] + gh[o + h] + b_ih[h] + b_hh[h]);
    const float z = sigmoidf_(gi[o + H + h] + gh[o + H + h] + b_ih[H + h] + b_hh[H + h]);
    const float n = tanhf(gi[o + 2 * H + h] + b_ih[2 * H + h]
                          + r * (gh[o + 2 * H + h] + b_hh[2 * H + h]));
    const float hn = (1.f - z) * n + z * h0[(size_t)b * H + h];
    hnew[(size_t)b * H + h] = hn;
    cbf[(size_t)b * 2 * H + h] = (__bf16)hn;
}

// =====================================================================
// fp32 tiled GEMM, W in [K][N] layout (bilinear: tmp = hnew @ bilin_w)
// =====================================================================
__global__ __launch_bounds__(256) void gemm_a64_kn(
    const float* __restrict__ A, const float* __restrict__ W,
    float* __restrict__ C, int K, int N, int ldc)
{
    __shared__ float As[64][68];
    __shared__ float Bs[64][68];
    const int tid = threadIdx.x;
    const int n0 = blockIdx.x * 64;
    const int tv = tid & 15;
    const int tb = tid >> 4;
    const int lrow = tid >> 2;
    const int lk0  = (tid & 3) * 16;

    float acc[4][4] = {{0.f, 0.f, 0.f, 0.f}};

    for (int kc = 0; kc < K; kc += 64) {
        #pragma unroll
        for (int i = 0; i < 4; ++i) {
            const float4 a = *(const float4*)(A + (size_t)lrow * K + kc + lk0 + 4 * i);
            As[lk0 + 4 * i + 0][lrow] = a.x;
            As[lk0 + 4 * i + 1][lrow] = a.y;
            As[lk0 + 4 * i + 2][lrow] = a.z;
            As[lk0 + 4 * i + 3][lrow] = a.w;
        }
        {
            const int v  = tid & 63;
            const int kg = tid >> 6;
            #pragma unroll
            for (int i = 0; i < 16; ++i) {
                const int kk = kg * 16 + i;
                Bs[kk][v] = (n0 + v < N) ? W[(size_t)(kc + kk) * N + n0 + v] : 0.f;
            }
        }
        __syncthreads();
        #pragma unroll 16
        for (int kk = 0; kk < 64; ++kk) {
            const float4 a = *(const float4*)&As[kk][tb * 4];
            const float4 b = *(const float4*)&Bs[kk][tv * 4];
            acc[0][0] += a.x * b.x; acc[0][1] += a.x * b.y; acc[0][2] += a.x * b.z; acc[0][3] += a.x * b.w;
            acc[1][0] += a.y * b.x; acc[1][1] += a.y * b.y; acc[1][2] += a.y * b.z; acc[1][3] += a.y * b.w;
            acc[2][0] += a.z * b.x; acc[2][1] += a.z * b.y; acc[2][2] += a.z * b.z; acc[2][3] += a.z * b.w;
            acc[3][0] += a.w * b.x; acc[3][1] += a.w * b.y; acc[3][2] += a.w * b.z; acc[3][3] += a.w * b.w;
        }
        __syncthreads();
    }
    #pragma unroll
    for (int i = 0; i < 4; ++i) {
        const int bb = tb * 4 + i;
        #pragma unroll
        for (int j = 0; j < 4; ++j) {
            const int n = n0 + tv * 4 + j;
            if (n < N) C[(size_t)bb * ldc + n] = acc[i][j];
        }
    }
}

// =====================================================================
// Flash attention partials, 4-wave blocks: grid (B, FP). Wave w handles
// s in {s0+w, s0+w+4, ...}. Per s: wave-wide dot (full 64-lane reduce),
// online (m,l,ctx) update; block-level combine via LDS -> ctxp/mp/lp.
// Raw energy written for the exact attn output later. enc read ONCE.
// =====================================================================
__global__ __launch_bounds__(256) void flash4(
    const float* __restrict__ tmp, const float* __restrict__ enc,
    const float* __restrict__ bilin_b, float* __restrict__ energy,
    float* __restrict__ ctxp, float* __restrict__ mp, float* __restrict__ lp,
    int S)
{
    const int b  = blockIdx.x;
    const int p  = blockIdx.y;
    const int wv = threadIdx.x >> 6;
    const int ln = threadIdx.x & 63;
    const int chunk = (S + FP - 1) / FP;
    const int s0 = p * chunk;
    int s1 = s0 + chunk; if (s1 > S) s1 = S;
    const int k0 = ln * 8;

    const float4 t0 = *(const float4*)(tmp + (size_t)b * H + k0);
    const float4 t1 = *(const float4*)(tmp + (size_t)b * H + k0 + 4);
    const float bb = bilin_b[0];

    float m = -1e30f, l = 0.f;
    float4 c0 = {0.f, 0.f, 0.f, 0.f}, c1 = {0.f, 0.f, 0.f, 0.f};

    for (int s = s0 + wv; s < s1; s += 4) {
        const float* e = enc + ((size_t)s * B + b) * H + k0;
        const float4 e0 = *(const float4*)(e);
        const float4 e1 = *(const float4*)(e + 4);
        float d = e0.x * t0.x + e0.y * t0.y + e0.z * t0.z + e0.w * t0.w
                + e1.x * t1.x + e1.y * t1.y + e1.z * t1.z + e1.w * t1.w;
        #pragma unroll
        for (int off = 32; off; off >>= 1) d += __shfl_xor(d, off);
        const float E = d + bb;
        if (ln == 0) energy[(size_t)s * B + b] = E;
        const float mn = fmaxf(m, E);
        const float sc = expf(m - mn);
        const float w  = expf(E - mn);
        l = l * sc + w;
        c0.x = c0.x * sc + w * e0.x; c0.y = c0.y * sc + w * e0.y;
        c0.z = c0.z * sc + w * e0.z; c0.w = c0.w * sc + w * e0.w;
        c1.x = c1.x * sc + w * e1.x; c1.y = c1.y * sc + w * e1.y;
        c1.z = c1.z * sc + w * e1.z; c1.w = c1.w * sc + w * e1.w;
        m = mn;
    }

    // ---- block combine across 4 waves ----
    __shared__ float sctx[4][H];
    __shared__ float sm4[4], sl4[4];
    *(float4*)&sctx[wv][k0]     = c0;
    *(float4*)&sctx[wv][k0 + 4] = c1;
    if (ln == 0) { sm4[wv] = m; sl4[wv] = l; }
    __syncthreads();
    const float bm = fmaxf(fmaxf(sm4[0], sm4[1]), fmaxf(sm4[2], sm4[3]));
    const float s0c = expf(sm4[0] - bm), s1c = expf(sm4[1] - bm);
    const float s2c = expf(sm4[2] - bm), s3c = expf(sm4[3] - bm);
    const float bl = sl4[0] * s0c + sl4[1] * s1c + sl4[2] * s2c + sl4[3] * s3c;
    for (int e = threadIdx.x; e < H; e += 256) {
        const float v = sctx[0][e] * s0c + sctx[1][e] * s1c
                      + sctx[2][e] * s2c + sctx[3][e] * s3c;
        ctxp[((size_t)b * FP + p) * H + e] = v;
    }
    if (threadIdx.x == 0) { mp[b * FP + p] = bm; lp[b * FP + p] = bl; }
}

// =====================================================================
// Combine flash partials: global (M,L) per b; context -> cbf[:, H:],
// attn[s][b] = exp(energy-M)/L -> d_out.
// =====================================================================
__global__ __launch_bounds__(256) void attn_combine(
    const float* __restrict__ mp, const float* __restrict__ lp,
    const float* __restrict__ ctxp, const float* __restrict__ energy,
    __bf16* __restrict__ cbf, float* __restrict__ attn, int S)
{
    const int b = blockIdx.x;
    const int t = threadIdx.x;
    __shared__ float sc_[FP];
    __shared__ float sM, sInvL;
    if (t == 0) {
        float M = -1e30f;
        #pragma unroll
        for (int p = 0; p < FP; ++p) M = fmaxf(M, mp[b * FP + p]);
        float L = 0.f;
        #pragma unroll
        for (int p = 0; p < FP; ++p) {
            const float s = expf(mp[b * FP + p] - M);
            sc_[p] = s;
            L += lp[b * FP + p] * s;
        }
        sM = M; sInvL = 1.f / L;
    }
    __syncthreads();
    const float M = sM, invL = sInvL;

    for (int e = t; e < H; e += 256) {
        float acc = 0.f;
        #pragma unroll
        for (int p = 0; p < FP; ++p)
            acc += ctxp[((size_t)b * FP + p) * H + e] * sc_[p];
        cbf[(size_t)b * 2 * H + H + e] = (__bf16)(acc * invL);
    }
    for (int s = t; s < S; s += 256)
        attn[(size_t)s * B + b] = expf(energy[(size_t)s * B + b] - M) * invL;
}

// =====================================================================
// Big output projection + fused partial log-softmax:
// C[64][N] = Ab[64][K](bf16) @ W[N][K](fp32)^T + bias; per block also
// reduces its 64x64 tile to per-row (max, sumexp) -> pm/ps[row][blk].
// W streams register-direct; A staged in LDS quarters (swizzled).
// =====================================================================
__global__ __launch_bounds__(256) void gemm_big(
    const __bf16* __restrict__ Ab,   // [64][K] bf16
    const float* __restrict__ W,     // [N][K] fp32
    const float* __restrict__ bias,
    float* __restrict__ C, float* __restrict__ pm, float* __restrict__ ps,
    int K, int N, int ldc)
{
    __shared__ __bf16 As[64 * 256];  // one 32 KB quarter (K-slice of 256)

    const int tid  = threadIdx.x;
    const int lane = tid & 63;
    const int wv   = tid >> 6;
    const int n0   = blockIdx.x * 64 + wv * 16;
    const int ln   = lane & 15;
    const int lk8  = (lane >> 4) << 3;

    int wr = n0 + ln;
    if (wr > N - 1) wr = N - 1;
    const float* wp = W + (size_t)wr * K + lk8;

    f32x4 acc[4] = {};
    const int NQ = K >> 8;

    for (int q = 0; q < NQ; ++q) {
        __syncthreads();
        #pragma unroll
        for (int i = 0; i < 8; ++i) {
            const int c   = tid + i * 256;
            const int row = c >> 5;
            const int eb  = (c & 31) << 3;
            const bf16x8 v = *(const bf16x8*)(Ab + (size_t)row * K + q * 256 + eb);
            const int off = (row << 8) + (eb ^ ((row & 7) << 3));
            *(bf16x8*)&As[off] = v;
        }
        __syncthreads();
        #pragma unroll
        for (int ks = 0; ks < 8; ++ks) {
            const float4 w0 = *(const float4*)(wp + q * 256 + ks * 32);
            const float4 w1 = *(const float4*)(wp + q * 256 + ks * 32 + 4);
            const bf16x8 bw = { (__bf16)w0.x, (__bf16)w0.y, (__bf16)w0.z, (__bf16)w0.w,
                                (__bf16)w1.x, (__bf16)w1.y, (__bf16)w1.z, (__bf16)w1.w };
            #pragma unroll
            for (int m = 0; m < 4; ++m) {
                const int row = m * 16 + ln;
                const int off = (row << 8) + ((ks * 32 + lk8) ^ ((row & 7) << 3));
                const bf16x8 af = *(const bf16x8*)&As[off];
                acc[m] = __builtin_amdgcn_mfma_f32_16x16x32_bf16(af, bw, acc[m], 0, 0, 0);
            }
        }
    }

    // ---- epilogue: store + per-row partial (max, sumexp) over 64 cols ----
    const int col = n0 + ln;
    const float bv = (col < N) ? bias[col] : 0.f;
    __syncthreads();                      // all MFMA reads of As done
    float* wmf = (float*)As;              // [4][64] per-wave row max
    float* wsf = wmf + 256;               // [4][64] per-wave row sumexp

    #pragma unroll
    for (int m = 0; m < 4; ++m) {
        #pragma unroll
        for (int j = 0; j < 4; ++j) {
            const int rr = m * 16 + (lane >> 4) * 4 + j;
            float v = acc[m][j] + bv;
            if (col < N) C[(size_t)rr * ldc + col] = v;
            else v = -1e30f;
            float vm = v;
            #pragma unroll
            for (int off = 8; off; off >>= 1) vm = fmaxf(vm, __shfl_xor(vm, off));
            float e = (col < N) ? expf(v - vm) : 0.f;
            #pragma unroll
            for (int off = 8; off; off >>= 1) e += __shfl_xor(e, off);
            if (ln == 0) {
                wmf[wv * 64 + rr] = vm;
                wsf[wv * 64 + rr] = e;
            }
        }
    }
    __syncthreads();
    if (tid < 64) {
        const float m0 = wmf[tid], m1 = wmf[64 + tid], m2 = wmf[128 + tid], m3 = wmf[192 + tid];
        const float bm = fmaxf(fmaxf(m0, m1), fmaxf(m2, m3));
        const float bs = wsf[tid] * expf(m0 - bm) + wsf[64 + tid] * expf(m1 - bm)
                       + wsf[128 + tid] * expf(m2 - bm) + wsf[192 + tid] * expf(m3 - bm);
        pm[(size_t)tid * gridDim.x + blockIdx.x] = bm;
        ps[(size_t)tid * gridDim.x + blockIdx.x] = bs;
    }
}

// =====================================================================
// Combine per-block softmax partials -> c[row] = M + log(L)
// =====================================================================
__global__ __launch_bounds__(256) void lsm_rowcombine(
    const float* __restrict__ pm, const float* __restrict__ ps,
    float* __restrict__ c, int NB)
{
    const int row = blockIdx.x;
    const int t = threadIdx.x;
    const float* pmr = pm + (size_t)row * NB;
    const float* psr = ps + (size_t)row * NB;
    __shared__ float sm_[4], ss_[4];

    float m = -1e30f;
    for (int i = t; i < NB; i += 256) m = fmaxf(m, pmr[i]);
    #pragma unroll
    for (int off = 32; off; off >>= 1) m = fmaxf(m, __shfl_xor(m, off));
    if ((t & 63) == 0) sm_[t >> 6] = m;
    __syncthreads();
    m = fmaxf(fmaxf(sm_[0], sm_[1]), fmaxf(sm_[2], sm_[3]));

    float s = 0.f;
    for (int i = t; i < NB; i += 256) s += psr[i] * expf(pmr[i] - m);
    #pragma unroll
    for (int off = 32; off; off >>= 1) s += __shfl_xor(s, off);
    if ((t & 63) == 0) ss_[t >> 6] = s;
    __syncthreads();
    if (t == 0) c[row] = m + logf(ss_[0] + ss_[1] + ss_[2] + ss_[3]);
}

__global__ __launch_bounds__(256) void lsm_apply(
    float* __restrict__ logits, const float* __restrict__ c, int V)
{
    const int b = blockIdx.y;
    const int i = blockIdx.x * 256 + threadIdx.x;
    const int V4 = V >> 2;
    if (i >= V4) return;
    float4* row = (float4*)(logits + (size_t)b * V);
    float4 v = row[i];
    const float cb = c[b];
    v.x -= cb; v.y -= cb; v.z -= cb; v.w -= cb;
    row[i] = v;
}

// =====================================================================
extern "C" void kernel_launch(void* const* d_in, const int* in_sizes, int n_in,
                              void* d_out, int out_size, void* d_ws, size_t ws_size,
                              hipStream_t stream)
{
    const float* embedded = (const float*)d_in[0];
    const float* hidden   = (const float*)d_in[1];
    const float* enc      = (const float*)d_in[2];
    const float* w_ih     = (const float*)d_in[3];
    const float* w_hh     = (const float*)d_in[4];
    const float* b_ih     = (const float*)d_in[5];
    const float* b_hh     = (const float*)d_in[6];
    const float* bilin_w  = (const float*)d_in[7];
    const float* bilin_b  = (const float*)d_in[8];
    const float* out_w    = (const float*)d_in[9];
    const float* out_b    = (const float*)d_in[10];
    float* out = (float*)d_out;

    const int S = in_sizes[2] / (B * H);      // 400
    const int V = in_sizes[9] / (2 * H);      // 50000
    const int NB = (V + 63) / 64;             // 782 gemm blocks

    float* logp = out;
    float* hnew = out + (size_t)B * V;
    float* attn = hnew + (size_t)B * H;

    float* ws     = (float*)d_ws;
    float* gi     = ws;                           // B*3H
    float* gh     = gi + (size_t)B * 3 * H;       // B*3H
    float* tmp    = gh + (size_t)B * 3 * H;       // B*H
    float* energy = tmp + (size_t)B * H;          // S*B
    float* ctxp   = energy + (size_t)S * B;       // B*FP*H
    float* mp     = ctxp + (size_t)B * FP * H;    // B*FP
    float* lp     = mp + (size_t)B * FP;          // B*FP
    float* pm     = lp + (size_t)B * FP;          // 64*NB
    float* ps     = pm + (size_t)64 * NB;         // 64*NB
    float* cb     = ps + (size_t)64 * NB;         // 64
    __bf16* cbf   = (__bf16*)(cb + 64);           // B*2H bf16

    // 1) gi & gh in one launch
    gemm_gigh<<<dim3(24, 2), 256, 0, stream>>>(embedded, hidden, w_ih, w_hh, gi, gh, H, 3 * H);

    // 2) GRU gates (+biases) -> hnew (d_out) + cbf[:, :H]
    gru_gates<<<B, H, 0, stream>>>(gi, gh, b_ih, b_hh, hidden, hnew, cbf);

    // 3) tmp = hnew @ bilin_w[0]
    gemm_a64_kn<<<H / 64, 256, 0, stream>>>(hnew, bilin_w, tmp, H, H, H);

    // 4) flash attention partials (enc read once)
    flash4<<<dim3(B, FP), 256, 0, stream>>>(tmp, enc, bilin_b, energy, ctxp, mp, lp, S);

    // 5) combine -> cbf[:, H:] + attn (d_out)
    attn_combine<<<B, 256, 0, stream>>>(mp, lp, ctxp, energy, cbf, attn, S);

    // 6) logits + fused partial log-softmax
    gemm_big<<<NB, 256, 0, stream>>>(cbf, out_w, out_b, logp, pm, ps, 2 * H, V, V);

    // 7) combine row partials -> c
    lsm_rowcombine<<<B, 256, 0, stream>>>(pm, ps, cb, NB);

    // 8) apply
    lsm_apply<<<dim3((V / 4 + 255) / 256, B), 256, 0, stream>>>(logp, cb, V);
}